// Round 7
// baseline (130.851 us; speedup 1.0000x reference)
//
#include <hip/hip_runtime.h>

// ArithmeticCompute: circle-encoded modular arithmetic over PRIMES.
// out[3][B*S][10][2] = {add, sub, mul} on the unit circle.
//
// R7 = DIAGNOSTIC ROUND. The R1-R6 totals are invariant (~75-85 us) under
// radical changes to compute volume and I/O pattern, and the kernel has
// never surfaced in the rocprof top-5 (cut ~41 us). To decompose
// total = harness_floor + kernel, the mul compute is repeated NREP=8x;
// reps 1..7 are weighted by a RUNTIME zero (kernel arg) with inputs
// perturbed by fmaf(zero, rep, x) -> no constant folding, no CSE, output
// bit-exact, same work every call. If total jumps ~8x-kernel, the kernel
// cost is real and the top-5 entry reveals VGPR/VALUBusy; if total barely
// moves, the kernel is ~free and we are at the harness floor.
//
// Algorithm per (pair, prime): quartet-folded softmax outer product
// (see R6): pair loop is (p-1)^2/2 FMAs via A=W[k]+W[p-k], B=W[k]-W[p-k].
// Block = 64 pairs x 10 primes (640 thr); wave w <-> prime w (uniform).
// I/O via dedicated float2 LDS tiles (validated R5).
// R3 lesson: no min-occupancy floor in __launch_bounds__ (forced 48-VGPR
// cap -> catastrophic scratch spill, VALUBusy 0.37%).

#define TEMP_LOG2E 1442.6950408889634f  // softmax_temperature * log2(e)
#define NREP 8

constexpr double PI_D = 3.14159265358979323846264338327950288;

constexpr double tay_cos(double x) {
    double x2 = x * x, term = 1.0, sum = 1.0;
    for (int k = 1; k <= 15; ++k) { term *= -x2 / double((2 * k - 1) * (2 * k)); sum += term; }
    return sum;
}
constexpr double tay_sin(double x) {
    double x2 = x * x, term = x, sum = x;
    for (int k = 1; k <= 15; ++k) { term *= -x2 / double((2 * k) * (2 * k + 1)); sum += term; }
    return sum;
}
constexpr double ang_red(int r, int P) {  // 2*pi*r/P reduced to [-pi, pi]
    double x = 2.0 * PI_D * double(r) / double(P);
    return (x > PI_D) ? x - 2.0 * PI_D : x;
}

template <int P> struct TabS { float c[P]; float s[P]; };
template <int P>
constexpr TabS<P> make_tabs() {
    TabS<P> t{};
    for (int r = 0; r < P; ++r) {
        t.c[r] = (float)(double(TEMP_LOG2E) * tay_cos(ang_red(r, P)));
        t.s[r] = (float)(double(TEMP_LOG2E) * tay_sin(ang_red(r, P)));
    }
    return t;
}
template <int P> struct TabE { float c[P / 2 + 1]; float s[P / 2 + 1]; };
template <int P>
constexpr TabE<P> make_tabe() {
    TabE<P> t{};
    for (int k = 0; k <= P / 2; ++k) {
        t.c[k] = (float)tay_cos(ang_red(k, P));
        t.s[k] = (float)tay_sin(ang_red(k, P));
    }
    return t;
}

template <int P>
__device__ __forceinline__ void mul_prime(float ca, float sa, float cb, float sb,
                                          float& oc, float& os) {
    static_assert(P % 2 == 1, "generic path requires odd P");
    constexpr int H = (P - 1) / 2;
    constexpr TabS<P> T = make_tabs<P>();
    constexpr TabE<P> E = make_tabe<P>();

    float ma = -1e30f, mb = -1e30f;
#pragma unroll
    for (int r = 0; r < P; ++r) {
        ma = fmaxf(ma, ca * T.c[r] + sa * T.s[r]);
        mb = fmaxf(mb, cb * T.c[r] + sb * T.s[r]);
    }

    float eb0 = __builtin_amdgcn_exp2f(cb * T.c[0] - mb);  // T.s[0] == 0
    float Sb = eb0;
    float ub[H], vb[H];
#pragma unroll
    for (int j = 1; j <= H; ++j) {
        float e1 = __builtin_amdgcn_exp2f(cb * T.c[j] + sb * T.s[j] - mb);
        float e2 = __builtin_amdgcn_exp2f(cb * T.c[P - j] + sb * T.s[P - j] - mb);
        Sb += e1 + e2;
        ub[j - 1] = e1 + e2;
        vb[j - 1] = e1 - e2;
    }

    float A[H], Bacc[H];
#pragma unroll
    for (int k = 0; k < H; ++k) { A[k] = 0.f; Bacc[k] = 0.f; }

    float ea0 = __builtin_amdgcn_exp2f(ca * T.c[0] - ma);
    float Sa = ea0;
#pragma unroll
    for (int i = 1; i <= H; ++i) {
        float f1 = __builtin_amdgcn_exp2f(ca * T.c[i] + sa * T.s[i] - ma);
        float f2 = __builtin_amdgcn_exp2f(ca * T.c[P - i] + sa * T.s[P - i] - ma);
        Sa += f1 + f2;
        const float ua = f1 + f2, va = f1 - f2;
#pragma unroll
        for (int j = 1; j <= H; ++j) {
            const int k0 = (i * j) % P;            // compile-time after unroll
            const int kr = (k0 <= H) ? k0 : P - k0;
            A[kr - 1] = fmaf(ua, ub[j - 1], A[kr - 1]);
            if (k0 <= H) Bacc[kr - 1] = fmaf(va,  vb[j - 1], Bacc[kr - 1]);
            else         Bacc[kr - 1] = fmaf(-va, vb[j - 1], Bacc[kr - 1]);
        }
    }

    const float W0 = ea0 * Sb + eb0 * (Sa - ea0);

    float accC = W0, accS = 0.f;
#pragma unroll
    for (int k = 1; k <= H; ++k) {
        accC = fmaf(A[k - 1],    E.c[k], accC);
        accS = fmaf(Bacc[k - 1], E.s[k], accS);
    }
    const float inv = 1.0f / (Sa * Sb);
    oc = accC * inv;
    os = accS * inv;
}

template <>
__device__ __forceinline__ void mul_prime<2>(float ca, float sa, float cb, float sb,
                                             float& oc, float& os) {
    const float ka = ca * TEMP_LOG2E, kb = cb * TEMP_LOG2E;
    const float ma = fabsf(ka), mb = fabsf(kb);
    const float ea0 = __builtin_amdgcn_exp2f(ka - ma);
    const float ea1 = __builtin_amdgcn_exp2f(-ka - ma);
    const float eb0 = __builtin_amdgcn_exp2f(kb - mb);
    const float eb1 = __builtin_amdgcn_exp2f(-kb - mb);
    const float Sa = ea0 + ea1, Sb = eb0 + eb1;
    const float W0 = ea0 * Sb + eb0 * Sa - ea0 * eb0;
    const float W1 = ea1 * eb1;
    oc = (W0 - W1) / (Sa * Sb);
    os = 0.f;
}

__global__ __launch_bounds__(640) void arith_kernel(const float* __restrict__ a,
                                                    const float* __restrict__ b,
                                                    float* __restrict__ out,
                                                    int n_pairs, float zero) {
    __shared__ float2 t0[64 * 11], t1[64 * 11];
    __shared__ float2 o0[64 * 11], o1[64 * 11], o2[64 * 11];

    const int t = threadIdx.x;
    const int pr = t / 10, of = t - pr * 10;
    const int li = pr * 11 + of;
    const int gf = blockIdx.x * 640 + t;

    t0[li] = ((const float2*)a)[gf];
    t1[li] = ((const float2*)b)[gf];
    __syncthreads();

    const int lane = t & 63;
    const int pi = t >> 6;                // wave-uniform prime index
    const int lc = lane * 11 + pi;
    const float2 av = t0[lc];
    const float2 bv = t1[lc];
    const float ca = av.x, sa = av.y, cb = bv.x, sb = bv.y;

    const float pcc = ca * cb, pss = sa * sb, psc = sa * cb, pcs = ca * sb;

    // Diagnostic repeat: rep 0 contributes with weight 1, reps 1..7 with
    // runtime-zero weight; inputs perturbed by fmaf(zero, rep, x) so the
    // replicas cannot be folded or CSE'd. Output is bit-exact vs 1 rep.
    float oc = 0.f, os = 0.f;
#pragma unroll 1
    for (int rep = 0; rep < NREP; ++rep) {
        const float w = (rep == 0) ? 1.0f : zero;
        const float frep = (float)rep;
        const float caR = fmaf(zero, frep, ca);
        const float saR = fmaf(zero, frep, sa);
        const float cbR = fmaf(zero, frep, cb);
        const float sbR = fmaf(zero, frep, sb);
        float tc, ts;
        switch (pi) {
            case 0: mul_prime<2>(caR, saR, cbR, sbR, tc, ts); break;
            case 1: mul_prime<3>(caR, saR, cbR, sbR, tc, ts); break;
            case 2: mul_prime<5>(caR, saR, cbR, sbR, tc, ts); break;
            case 3: mul_prime<7>(caR, saR, cbR, sbR, tc, ts); break;
            case 4: mul_prime<11>(caR, saR, cbR, sbR, tc, ts); break;
            case 5: mul_prime<13>(caR, saR, cbR, sbR, tc, ts); break;
            case 6: mul_prime<17>(caR, saR, cbR, sbR, tc, ts); break;
            case 7: mul_prime<19>(caR, saR, cbR, sbR, tc, ts); break;
            case 8: mul_prime<23>(caR, saR, cbR, sbR, tc, ts); break;
            default: mul_prime<29>(caR, saR, cbR, sbR, tc, ts); break;
        }
        oc = fmaf(w, tc, oc);
        os = fmaf(w, ts, os);
    }

    o0[lc] = make_float2(pcc - pss, psc + pcs);
    o1[lc] = make_float2(pcc + pss, psc - pcs);
    o2[lc] = make_float2(oc, os);
    __syncthreads();

    const int planef2 = n_pairs * 10;
    float2* o = (float2*)out;
    o[gf]               = o0[li];
    o[planef2 + gf]     = o1[li];
    o[2 * planef2 + gf] = o2[li];
}

extern "C" void kernel_launch(void* const* d_in, const int* in_sizes, int n_in,
                              void* d_out, int out_size, void* d_ws, size_t ws_size,
                              hipStream_t stream) {
    const float* a = (const float*)d_in[0];
    const float* b = (const float*)d_in[1];
    float* out = (float*)d_out;
    const int n_pairs = in_sizes[0] / 20;   // B*S = 65536 (multiple of 64)
    const int n_groups = n_pairs / 64;      // 1024 blocks

    dim3 block(640);
    dim3 grid(n_groups);
    arith_kernel<<<grid, block, 0, stream>>>(a, b, out, n_pairs, 0.0f);
}

// Round 8
// 74.343 us; speedup vs baseline: 1.7601x; 1.7601x over previous
//
#include <hip/hip_runtime.h>

// ArithmeticCompute: circle-encoded modular arithmetic over PRIMES.
// out[3][B*S][10][2] = {add, sub, mul} on the unit circle.
//
// Block = one 64-pair group x all 10 primes (640 threads, 10 waves).
// Wave w handles prime index w -> wave-uniform template dispatch.
//
// R7 diagnostic findings baked in here:
//  - The compiler self-capped at 64 VGPRs (p=29 path needs ~80 live) and
//    spilled; that, not I/O, made the kernel ~21 us in R1-R6.
//    __launch_bounds__(640, 2) raises the cap (~102+) -> no spill.
//    (R3: (640,5) forced a 48-VGPR cap -> catastrophic scratch spill.)
//  - add/sub are ELEMENTWISE: computed and stored coalesced directly by
//    the staging thread in phase 1 (before any barrier, overlapping the
//    mul compute). Only mul needs the LDS transpose: 3 buffers, 16.9 KB.
//
// mul per (pair, prime): quartet-folded softmax outer product (R6):
// pair residues i<->p-i, j<->p-j; A[k]=W[k]+W[p-k] += ua*ub,
// B[k]=W[k]-W[p-k] +-= va*vb; out needs only sum(A*cos), sum(B*sin).
// Pair loop = (p-1)^2/2 FMAs.

#define TEMP_LOG2E 1442.6950408889634f  // softmax_temperature * log2(e)

constexpr double PI_D = 3.14159265358979323846264338327950288;

constexpr double tay_cos(double x) {
    double x2 = x * x, term = 1.0, sum = 1.0;
    for (int k = 1; k <= 15; ++k) { term *= -x2 / double((2 * k - 1) * (2 * k)); sum += term; }
    return sum;
}
constexpr double tay_sin(double x) {
    double x2 = x * x, term = x, sum = x;
    for (int k = 1; k <= 15; ++k) { term *= -x2 / double((2 * k) * (2 * k + 1)); sum += term; }
    return sum;
}
constexpr double ang_red(int r, int P) {  // 2*pi*r/P reduced to [-pi, pi]
    double x = 2.0 * PI_D * double(r) / double(P);
    return (x > PI_D) ? x - 2.0 * PI_D : x;
}

template <int P> struct TabS { float c[P]; float s[P]; };
template <int P>
constexpr TabS<P> make_tabs() {
    TabS<P> t{};
    for (int r = 0; r < P; ++r) {
        t.c[r] = (float)(double(TEMP_LOG2E) * tay_cos(ang_red(r, P)));
        t.s[r] = (float)(double(TEMP_LOG2E) * tay_sin(ang_red(r, P)));
    }
    return t;
}
template <int P> struct TabE { float c[P / 2 + 1]; float s[P / 2 + 1]; };
template <int P>
constexpr TabE<P> make_tabe() {
    TabE<P> t{};
    for (int k = 0; k <= P / 2; ++k) {
        t.c[k] = (float)tay_cos(ang_red(k, P));
        t.s[k] = (float)tay_sin(ang_red(k, P));
    }
    return t;
}

template <int P>
__device__ __forceinline__ void mul_prime(float ca, float sa, float cb, float sb,
                                          float& oc, float& os) {
    static_assert(P % 2 == 1, "generic path requires odd P");
    constexpr int H = (P - 1) / 2;
    constexpr TabS<P> T = make_tabs<P>();
    constexpr TabE<P> E = make_tabe<P>();

    // Pass 1: maxes of the scaled similarities (overflow guard).
    float ma = -1e30f, mb = -1e30f;
#pragma unroll
    for (int r = 0; r < P; ++r) {
        ma = fmaxf(ma, ca * T.c[r] + sa * T.s[r]);
        mb = fmaxf(mb, cb * T.c[r] + sb * T.s[r]);
    }

    // Pass 2: b-side folded softmax numerators.
    float eb0 = __builtin_amdgcn_exp2f(cb * T.c[0] - mb);  // T.s[0] == 0
    float Sb = eb0;
    float ub[H], vb[H];
#pragma unroll
    for (int j = 1; j <= H; ++j) {
        float e1 = __builtin_amdgcn_exp2f(cb * T.c[j] + sb * T.s[j] - mb);
        float e2 = __builtin_amdgcn_exp2f(cb * T.c[P - j] + sb * T.s[P - j] - mb);
        Sb += e1 + e2;
        ub[j - 1] = e1 + e2;
        vb[j - 1] = e1 - e2;
    }

    // Pass 3: a-side outer loop (recomputed, nothing stored) + pair loop.
    float A[H], Bacc[H];
#pragma unroll
    for (int k = 0; k < H; ++k) { A[k] = 0.f; Bacc[k] = 0.f; }

    float ea0 = __builtin_amdgcn_exp2f(ca * T.c[0] - ma);
    float Sa = ea0;
#pragma unroll
    for (int i = 1; i <= H; ++i) {
        float f1 = __builtin_amdgcn_exp2f(ca * T.c[i] + sa * T.s[i] - ma);
        float f2 = __builtin_amdgcn_exp2f(ca * T.c[P - i] + sa * T.s[P - i] - ma);
        Sa += f1 + f2;
        const float ua = f1 + f2, va = f1 - f2;
#pragma unroll
        for (int j = 1; j <= H; ++j) {
            const int k0 = (i * j) % P;            // compile-time after unroll
            const int kr = (k0 <= H) ? k0 : P - k0;
            A[kr - 1] = fmaf(ua, ub[j - 1], A[kr - 1]);
            if (k0 <= H) Bacc[kr - 1] = fmaf(va,  vb[j - 1], Bacc[kr - 1]);
            else         Bacc[kr - 1] = fmaf(-va, vb[j - 1], Bacc[kr - 1]);
        }
    }

    // Zero row/column: contributes only to W[0].
    const float W0 = ea0 * Sb + eb0 * (Sa - ea0);

    // Epilogue: re-encode. cos is even in k, sin is odd.
    float accC = W0, accS = 0.f;
#pragma unroll
    for (int k = 1; k <= H; ++k) {
        accC = fmaf(A[k - 1],    E.c[k], accC);
        accS = fmaf(Bacc[k - 1], E.s[k], accS);
    }
    const float inv = 1.0f / (Sa * Sb);
    oc = accC * inv;
    os = accS * inv;
}

// P = 2: closed form (templates (1,0), (-1,0); sin terms vanish).
template <>
__device__ __forceinline__ void mul_prime<2>(float ca, float sa, float cb, float sb,
                                             float& oc, float& os) {
    const float ka = ca * TEMP_LOG2E, kb = cb * TEMP_LOG2E;
    const float ma = fabsf(ka), mb = fabsf(kb);
    const float ea0 = __builtin_amdgcn_exp2f(ka - ma);
    const float ea1 = __builtin_amdgcn_exp2f(-ka - ma);
    const float eb0 = __builtin_amdgcn_exp2f(kb - mb);
    const float eb1 = __builtin_amdgcn_exp2f(-kb - mb);
    const float Sa = ea0 + ea1, Sb = eb0 + eb1;
    const float W0 = ea0 * Sb + eb0 * Sa - ea0 * eb0;
    const float W1 = ea1 * eb1;
    oc = (W0 - W1) / (Sa * Sb);
    os = 0.f;
}

__global__ __launch_bounds__(640, 2) void arith_kernel(const float* __restrict__ a,
                                                       const float* __restrict__ b,
                                                       float* __restrict__ out,
                                                       int n_pairs) {
    // float2 tiles: 64 rows (pairs) x 11 slots (10 primes + 1 pad).
    __shared__ float2 t0[64 * 11], t1[64 * 11];  // inputs a, b
    __shared__ float2 o2[64 * 11];               // mul result

    const int t = threadIdx.x;                // 0..639 == float2 index in tile
    const int pr = t / 10, of = t - pr * 10;  // staging row (pair), col (prime)
    const int li = pr * 11 + of;              // staging slot
    const int gf = blockIdx.x * 640 + t;      // global float2 index
    const int planef2 = n_pairs * 10;         // plane size in float2
    float2* o = (float2*)out;

    // Phase 1: coalesced load; add/sub are elementwise -> store directly
    // (coalesced, pre-barrier, overlaps later compute); stage for mul.
    {
        const float2 av = ((const float2*)a)[gf];
        const float2 bv = ((const float2*)b)[gf];
        t0[li] = av;
        t1[li] = bv;
        const float pcc = av.x * bv.x, pss = av.y * bv.y;
        const float psc = av.y * bv.x, pcs = av.x * bv.y;
        o[gf]           = make_float2(pcc - pss, psc + pcs);  // add
        o[planef2 + gf] = make_float2(pcc + pss, psc - pcs);  // sub
    }
    __syncthreads();

    // Phase 2: per-(pair, prime) mul. Wave pi handles prime pi (uniform).
    {
        const int lane = t & 63;
        const int pi = t >> 6;
        const int lc = lane * 11 + pi;
        const float2 av = t0[lc];
        const float2 bv = t1[lc];
        float oc, os;
        switch (pi) {
            case 0: mul_prime<2>(av.x, av.y, bv.x, bv.y, oc, os); break;
            case 1: mul_prime<3>(av.x, av.y, bv.x, bv.y, oc, os); break;
            case 2: mul_prime<5>(av.x, av.y, bv.x, bv.y, oc, os); break;
            case 3: mul_prime<7>(av.x, av.y, bv.x, bv.y, oc, os); break;
            case 4: mul_prime<11>(av.x, av.y, bv.x, bv.y, oc, os); break;
            case 5: mul_prime<13>(av.x, av.y, bv.x, bv.y, oc, os); break;
            case 6: mul_prime<17>(av.x, av.y, bv.x, bv.y, oc, os); break;
            case 7: mul_prime<19>(av.x, av.y, bv.x, bv.y, oc, os); break;
            case 8: mul_prime<23>(av.x, av.y, bv.x, bv.y, oc, os); break;
            default: mul_prime<29>(av.x, av.y, bv.x, bv.y, oc, os); break;
        }
        o2[lc] = make_float2(oc, os);
    }
    __syncthreads();

    // Phase 3: coalesced LDS -> global for the mul plane.
    o[2 * planef2 + gf] = o2[li];
}

extern "C" void kernel_launch(void* const* d_in, const int* in_sizes, int n_in,
                              void* d_out, int out_size, void* d_ws, size_t ws_size,
                              hipStream_t stream) {
    const float* a = (const float*)d_in[0];
    const float* b = (const float*)d_in[1];
    float* out = (float*)d_out;
    const int n_pairs = in_sizes[0] / 20;   // B*S = 65536 (multiple of 64)
    const int n_groups = n_pairs / 64;      // 1024 blocks

    dim3 block(640);
    dim3 grid(n_groups);
    arith_kernel<<<grid, block, 0, stream>>>(a, b, out, n_pairs);
}

// Round 10
// 69.357 us; speedup vs baseline: 1.8866x; 1.0719x over previous
//
#include <hip/hip_runtime.h>

// ArithmeticCompute: circle-encoded modular arithmetic over PRIMES.
// out[3][B*S][10][2] = {add, sub, mul} on the unit circle.
//
// R10 = R9 structure with the staging-loop extent FIXED (5 iters, not 10:
// block owns 128 pairs = 1280 float2, 256 threads x 5). R9's 10-iter loop
// overran the LDS tiles (corrupting mul inputs) and, in the last block,
// wrote past the plane boundary (absmax 8.1).
//
// Structure: UNIFORM WAVES via prime-set partition.
//   Block = 256 threads = 4 waves, owns 128 pairs.
//   Waves 0,1: subset A = primes {2,13,17,29}  (~1256 ops/thread)
//   Waves 2,3: subset B = primes {3,5,7,11,19,23} (~1230 ops/thread)
//   -> ~equal work per wave (2% skew vs 2.8x in one-prime-per-wave), no
//   straggler at the block barrier, one code path per subset (I$ halved),
//   zero intra-wave divergence (subset choice is wave-uniform). Prime
//   bodies run sequentially per thread -> peak live regs ~= p29 body
//   (~80); (256,2) caps at 256 -> no spill (R3/R7: caps of 48/64 caused
//   catastrophic scratch spill).
//
// I/O (validated R5/R8): coalesced float2 loads; add/sub are elementwise,
// computed from registers and stored coalesced during staging (phase 1);
// only mul round-trips LDS (row stride 11 float2).
//
// mul per (pair, prime): quartet-folded softmax outer product (R6):
// pair residues i<->p-i, j<->p-j; A[k]=W[k]+W[p-k] += ua*ub,
// B[k]=W[k]-W[p-k] +-= va*vb; out needs only sum(A*cos), sum(B*sin).
// Pair loop = (p-1)^2/2 FMAs.

#define TEMP_LOG2E 1442.6950408889634f  // softmax_temperature * log2(e)

constexpr double PI_D = 3.14159265358979323846264338327950288;

constexpr double tay_cos(double x) {
    double x2 = x * x, term = 1.0, sum = 1.0;
    for (int k = 1; k <= 15; ++k) { term *= -x2 / double((2 * k - 1) * (2 * k)); sum += term; }
    return sum;
}
constexpr double tay_sin(double x) {
    double x2 = x * x, term = x, sum = x;
    for (int k = 1; k <= 15; ++k) { term *= -x2 / double((2 * k) * (2 * k + 1)); sum += term; }
    return sum;
}
constexpr double ang_red(int r, int P) {  // 2*pi*r/P reduced to [-pi, pi]
    double x = 2.0 * PI_D * double(r) / double(P);
    return (x > PI_D) ? x - 2.0 * PI_D : x;
}

template <int P> struct TabS { float c[P]; float s[P]; };
template <int P>
constexpr TabS<P> make_tabs() {
    TabS<P> t{};
    for (int r = 0; r < P; ++r) {
        t.c[r] = (float)(double(TEMP_LOG2E) * tay_cos(ang_red(r, P)));
        t.s[r] = (float)(double(TEMP_LOG2E) * tay_sin(ang_red(r, P)));
    }
    return t;
}
template <int P> struct TabE { float c[P / 2 + 1]; float s[P / 2 + 1]; };
template <int P>
constexpr TabE<P> make_tabe() {
    TabE<P> t{};
    for (int k = 0; k <= P / 2; ++k) {
        t.c[k] = (float)tay_cos(ang_red(k, P));
        t.s[k] = (float)tay_sin(ang_red(k, P));
    }
    return t;
}

template <int P>
__device__ __forceinline__ void mul_prime(float ca, float sa, float cb, float sb,
                                          float& oc, float& os) {
    static_assert(P % 2 == 1, "generic path requires odd P");
    constexpr int H = (P - 1) / 2;
    constexpr TabS<P> T = make_tabs<P>();
    constexpr TabE<P> E = make_tabe<P>();

    // Pass 1: maxes of the scaled similarities (overflow guard).
    float ma = -1e30f, mb = -1e30f;
#pragma unroll
    for (int r = 0; r < P; ++r) {
        ma = fmaxf(ma, ca * T.c[r] + sa * T.s[r]);
        mb = fmaxf(mb, cb * T.c[r] + sb * T.s[r]);
    }

    // Pass 2: b-side folded softmax numerators.
    float eb0 = __builtin_amdgcn_exp2f(cb * T.c[0] - mb);  // T.s[0] == 0
    float Sb = eb0;
    float ub[H], vb[H];
#pragma unroll
    for (int j = 1; j <= H; ++j) {
        float e1 = __builtin_amdgcn_exp2f(cb * T.c[j] + sb * T.s[j] - mb);
        float e2 = __builtin_amdgcn_exp2f(cb * T.c[P - j] + sb * T.s[P - j] - mb);
        Sb += e1 + e2;
        ub[j - 1] = e1 + e2;
        vb[j - 1] = e1 - e2;
    }

    // Pass 3: a-side outer loop (recomputed, nothing stored) + pair loop.
    float A[H], Bacc[H];
#pragma unroll
    for (int k = 0; k < H; ++k) { A[k] = 0.f; Bacc[k] = 0.f; }

    float ea0 = __builtin_amdgcn_exp2f(ca * T.c[0] - ma);
    float Sa = ea0;
#pragma unroll
    for (int i = 1; i <= H; ++i) {
        float f1 = __builtin_amdgcn_exp2f(ca * T.c[i] + sa * T.s[i] - ma);
        float f2 = __builtin_amdgcn_exp2f(ca * T.c[P - i] + sa * T.s[P - i] - ma);
        Sa += f1 + f2;
        const float ua = f1 + f2, va = f1 - f2;
#pragma unroll
        for (int j = 1; j <= H; ++j) {
            const int k0 = (i * j) % P;            // compile-time after unroll
            const int kr = (k0 <= H) ? k0 : P - k0;
            A[kr - 1] = fmaf(ua, ub[j - 1], A[kr - 1]);
            if (k0 <= H) Bacc[kr - 1] = fmaf(va,  vb[j - 1], Bacc[kr - 1]);
            else         Bacc[kr - 1] = fmaf(-va, vb[j - 1], Bacc[kr - 1]);
        }
    }

    // Zero row/column: contributes only to W[0].
    const float W0 = ea0 * Sb + eb0 * (Sa - ea0);

    // Epilogue: re-encode. cos is even in k, sin is odd.
    float accC = W0, accS = 0.f;
#pragma unroll
    for (int k = 1; k <= H; ++k) {
        accC = fmaf(A[k - 1],    E.c[k], accC);
        accS = fmaf(Bacc[k - 1], E.s[k], accS);
    }
    const float inv = 1.0f / (Sa * Sb);
    oc = accC * inv;
    os = accS * inv;
}

// P = 2: closed form (templates (1,0), (-1,0); sin terms vanish).
template <>
__device__ __forceinline__ void mul_prime<2>(float ca, float sa, float cb, float sb,
                                             float& oc, float& os) {
    const float ka = ca * TEMP_LOG2E, kb = cb * TEMP_LOG2E;
    const float ma = fabsf(ka), mb = fabsf(kb);
    const float ea0 = __builtin_amdgcn_exp2f(ka - ma);
    const float ea1 = __builtin_amdgcn_exp2f(-ka - ma);
    const float eb0 = __builtin_amdgcn_exp2f(kb - mb);
    const float eb1 = __builtin_amdgcn_exp2f(-kb - mb);
    const float Sa = ea0 + ea1, Sb = eb0 + eb1;
    const float W0 = ea0 * Sb + eb0 * Sa - ea0 * eb0;
    const float W1 = ea1 * eb1;
    oc = (W0 - W1) / (Sa * Sb);
    os = 0.f;
}

__global__ __launch_bounds__(256, 2) void arith_kernel(const float* __restrict__ a,
                                                       const float* __restrict__ b,
                                                       float* __restrict__ out,
                                                       int n_pairs) {
    // 128 pairs x 11 float2 slots (10 primes + pad).
    __shared__ float2 ta[128 * 11], tb[128 * 11], om[128 * 11];

    const int t = threadIdx.x;                 // 0..255
    const int gbase = blockIdx.x * 1280;       // block base in float2
    const int planef2 = n_pairs * 10;          // plane size in float2
    float2* o = (float2*)out;

    // Phase 1: coalesced load + stage (block extent = 1280 float2 = 5 iters).
    // add/sub are elementwise: computed from registers, stored coalesced now.
#pragma unroll
    for (int it = 0; it < 5; ++it) {
        const int idx = it * 256 + t;          // 0..1279
        const int pr = idx / 10, of = idx - pr * 10;
        const int sl = pr * 11 + of;
        const float2 av = ((const float2*)a)[gbase + idx];
        const float2 bv = ((const float2*)b)[gbase + idx];
        ta[sl] = av;
        tb[sl] = bv;
        const float pcc = av.x * bv.x, pss = av.y * bv.y;
        const float psc = av.y * bv.x, pcs = av.x * bv.y;
        o[gbase + idx]            = make_float2(pcc - pss, psc + pcs);  // add
        o[planef2 + gbase + idx]  = make_float2(pcc + pss, psc - pcs);  // sub
    }
    __syncthreads();

    // Phase 2: uniform waves. Waves 0,1 -> subset A on rows 0-63/64-127;
    // waves 2,3 -> subset B on rows 0-63/64-127. Wave-uniform choice.
    {
        const int lane = t & 63;
        const int row = ((t >> 6) & 1) * 64 + lane;  // pair row 0..127
        const int rb = row * 11;

#define DO_PRIME(P, OFI)                                                     \
        {                                                                    \
            const float2 av = ta[rb + (OFI)];                                \
            const float2 bv = tb[rb + (OFI)];                                \
            float oc, os;                                                    \
            mul_prime<P>(av.x, av.y, bv.x, bv.y, oc, os);                    \
            om[rb + (OFI)] = make_float2(oc, os);                            \
        }

        if (t < 128) {
            // Subset A: {2, 13, 17, 29} ~= 1256 ops
            DO_PRIME(29, 9)
            DO_PRIME(17, 6)
            DO_PRIME(13, 5)
            DO_PRIME(2, 0)
        } else {
            // Subset B: {3, 5, 7, 11, 19, 23} ~= 1230 ops
            DO_PRIME(23, 8)
            DO_PRIME(19, 7)
            DO_PRIME(11, 4)
            DO_PRIME(7, 3)
            DO_PRIME(5, 2)
            DO_PRIME(3, 1)
        }
#undef DO_PRIME
    }
    __syncthreads();

    // Phase 3: coalesced LDS -> global for the mul plane (5 iters).
#pragma unroll
    for (int it = 0; it < 5; ++it) {
        const int idx = it * 256 + t;
        const int pr = idx / 10, of = idx - pr * 10;
        o[2 * planef2 + gbase + idx] = om[pr * 11 + of];
    }
}

extern "C" void kernel_launch(void* const* d_in, const int* in_sizes, int n_in,
                              void* d_out, int out_size, void* d_ws, size_t ws_size,
                              hipStream_t stream) {
    const float* a = (const float*)d_in[0];
    const float* b = (const float*)d_in[1];
    float* out = (float*)d_out;
    const int n_pairs = in_sizes[0] / 20;   // B*S = 65536 (multiple of 128)
    const int n_blocks = n_pairs / 128;     // 512 blocks of 256 threads

    dim3 block(256);
    dim3 grid(n_blocks);
    arith_kernel<<<grid, block, 0, stream>>>(a, b, out, n_pairs);
}